// Round 7
// baseline (368.835 us; speedup 1.0000x reference)
//
#include <hip/hip_runtime.h>

#define N_NODES 50000
#define N_EDGES 800000
#define N_GRAPHS 64
#define DH 128
#define DOUT 32

typedef __attribute__((ext_vector_type(8))) short bf16x8;
typedef __attribute__((ext_vector_type(4))) float f32x4;

__device__ __forceinline__ unsigned short f2bf(float f) {
    union { float f; unsigned int u; } x;
    x.f = f;
    unsigned int u = x.u;
    u += 0x7FFFu + ((u >> 16) & 1u);  // round-to-nearest-even
    return (unsigned short)(u >> 16);
}

__device__ __forceinline__ float bf2f(unsigned short s) {
    union { unsigned int u; float f; } x;
    x.u = ((unsigned int)s) << 16;
    return x.f;
}

// ---------------- stats: column sums / sumsq (no atomics, 2-stage) ----------------
#define STAT_BLKS 512
__global__ __launch_bounds__(256) void stats_kernel(const float* __restrict__ x,
                                                    float* __restrict__ partial) {
    __shared__ float4 shs[256];
    __shared__ float4 shq[256];
    const int tid = threadIdx.x;
    const int rowgrp = tid >> 5;
    const int cq = tid & 31;
    float4 s = make_float4(0.f, 0.f, 0.f, 0.f);
    float4 q = make_float4(0.f, 0.f, 0.f, 0.f);
#pragma unroll 4
    for (int r = blockIdx.x * 8 + rowgrp; r < N_NODES; r += STAT_BLKS * 8) {
        const float4 v = *reinterpret_cast<const float4*>(x + (size_t)r * DH + cq * 4);
        s.x += v.x; s.y += v.y; s.z += v.z; s.w += v.w;
        q.x = fmaf(v.x, v.x, q.x); q.y = fmaf(v.y, v.y, q.y);
        q.z = fmaf(v.z, v.z, q.z); q.w = fmaf(v.w, v.w, q.w);
    }
    shs[tid] = s; shq[tid] = q;
    __syncthreads();
    for (int off = 128; off >= 32; off >>= 1) {
        if (tid < off) {
            float4 a = shs[tid], b = shs[tid + off];
            a.x += b.x; a.y += b.y; a.z += b.z; a.w += b.w;
            shs[tid] = a;
            float4 c = shq[tid], d = shq[tid + off];
            c.x += d.x; c.y += d.y; c.z += d.z; c.w += d.w;
            shq[tid] = c;
        }
        __syncthreads();
    }
    if (tid < 32) {
        const float4 a = shs[tid];
        const float4 c = shq[tid];
        const float sv[4] = {a.x, a.y, a.z, a.w};
        const float qv[4] = {c.x, c.y, c.z, c.w};
#pragma unroll
        for (int j = 0; j < 4; ++j) {
            const int col = tid * 4 + j;
            partial[(size_t)col * STAT_BLKS + blockIdx.x] = sv[j];
            partial[(size_t)(128 + col) * STAT_BLKS + blockIdx.x] = qv[j];
        }
    }
}

// stat layout: [256:384) mu, [384:512) inv_sd
__global__ __launch_bounds__(128) void finalize_stats_kernel(const float* __restrict__ partial,
                                                             float* __restrict__ stat) {
    const int c = threadIdx.x;
    const float4* ps = reinterpret_cast<const float4*>(partial + (size_t)c * STAT_BLKS);
    const float4* pq = reinterpret_cast<const float4*>(partial + (size_t)(128 + c) * STAT_BLKS);
    float s = 0.f, q = 0.f;
#pragma unroll 8
    for (int b = 0; b < STAT_BLKS / 4; ++b) {
        const float4 v = ps[b];
        s += v.x + v.y + v.z + v.w;
        const float4 w = pq[b];
        q += w.x + w.y + w.z + w.w;
    }
    const float inv_n = 1.0f / (float)N_NODES;
    const float mu = s * inv_n;
    const float var = q * inv_n - mu * mu;
    const float sd = sqrtf(fmaxf(var, 1e-20f));
    stat[256 + c] = mu;
    stat[384 + c] = 1.0f / sd;
}

// standardize -> bf16 h
__global__ void standardize_kernel(const float* __restrict__ x,
                                   const float* __restrict__ stat,
                                   unsigned short* __restrict__ h) {
    const size_t i = (size_t)blockIdx.x * blockDim.x + threadIdx.x;  // float4 index
    const int c4 = (int)(i & 31) << 2;
    const float4 v = reinterpret_cast<const float4*>(x)[i];
    const float4 m = *reinterpret_cast<const float4*>(stat + 256 + c4);
    const float4 is = *reinterpret_cast<const float4*>(stat + 384 + c4);
    ushort4 o;
    o.x = f2bf((v.x - m.x) * is.x);
    o.y = f2bf((v.y - m.y) * is.y);
    o.z = f2bf((v.z - m.z) * is.z);
    o.w = f2bf((v.w - m.w) * is.w);
    reinterpret_cast<ushort4*>(h)[i] = o;
}

// ---------------- CSR build ----------------
__global__ void count_deg_kernel(const int* __restrict__ dst, int* __restrict__ deg_i) {
    int e = blockIdx.x * blockDim.x + threadIdx.x;
    if (e < N_EDGES) atomicAdd(&deg_i[dst[e]], 1);
}

#define SCAN_BLK 256
#define SCAN_NBLK ((N_NODES + SCAN_BLK - 1) / SCAN_BLK)  // 196

__global__ __launch_bounds__(SCAN_BLK) void scan_local_kernel(const int* __restrict__ deg_i,
                                                              int* __restrict__ row_ptr,
                                                              int* __restrict__ bsum) {
    __shared__ int sh[SCAN_BLK];
    const int tid = threadIdx.x;
    const int idx = blockIdx.x * SCAN_BLK + tid;
    const int v = (idx < N_NODES) ? deg_i[idx] : 0;
    sh[tid] = v;
    __syncthreads();
#pragma unroll
    for (int off = 1; off < SCAN_BLK; off <<= 1) {
        const int t = (tid >= off) ? sh[tid - off] : 0;
        __syncthreads();
        sh[tid] += t;
        __syncthreads();
    }
    if (idx < N_NODES) row_ptr[idx] = sh[tid] - v;
    if (tid == SCAN_BLK - 1) bsum[blockIdx.x] = sh[tid];
}

__global__ __launch_bounds__(SCAN_BLK) void scan_bsum_kernel(int* __restrict__ bsum) {
    __shared__ int sh[SCAN_BLK];
    const int tid = threadIdx.x;
    const int v = (tid < SCAN_NBLK) ? bsum[tid] : 0;
    sh[tid] = v;
    __syncthreads();
#pragma unroll
    for (int off = 1; off < SCAN_BLK; off <<= 1) {
        const int t = (tid >= off) ? sh[tid - off] : 0;
        __syncthreads();
        sh[tid] += t;
        __syncthreads();
    }
    if (tid < SCAN_NBLK) bsum[tid] = sh[tid] - v;
}

__global__ __launch_bounds__(SCAN_BLK) void scan_finalize_kernel(const int* __restrict__ deg_i,
                                                                 const int* __restrict__ bsum,
                                                                 int* __restrict__ row_ptr,
                                                                 int* __restrict__ cursor,
                                                                 float* __restrict__ deg_inv) {
    const int tid = threadIdx.x;
    const int idx = blockIdx.x * SCAN_BLK + tid;
    if (idx < N_NODES) {
        const int excl = row_ptr[idx] + bsum[blockIdx.x];
        row_ptr[idx] = excl;
        cursor[idx] = excl;
        const int d = deg_i[idx];
        deg_inv[idx] = 1.0f / (float)(d > 1 ? d : 1);
    }
    if (idx == 0) row_ptr[N_NODES] = N_EDGES;
}

__global__ void scatter_kernel(const int* __restrict__ src, const int* __restrict__ dst,
                               int* __restrict__ cursor, int* __restrict__ csr_src) {
    int e = blockIdx.x * blockDim.x + threadIdx.x;
    if (e < N_EDGES) {
        const int pos = atomicAdd(&cursor[dst[e]], 1);
        csr_src[pos] = src[e];
    }
}

// ---------------- aggregation via CSR (bf16 in, fp32 accum, bf16 out) ----------------
// agg[n] = (useScale ? deg_inv[n] : 1) * sum_{e in in(n)} h[src[e]]
__global__ __launch_bounds__(256) void aggregate_csr_kernel(const unsigned short* __restrict__ h,
                                                            const int* __restrict__ row_ptr,
                                                            const int* __restrict__ csr_src,
                                                            const float* __restrict__ deg_inv,
                                                            unsigned short* __restrict__ agg,
                                                            const int useScale) {
    const int node = blockIdx.x * 4 + (threadIdx.x >> 6);  // one wave per node
    if (node >= N_NODES) return;
    const int lane = threadIdx.x & 63;
    const int beg = row_ptr[node];
    const int end = row_ptr[node + 1];
    float a0 = 0.f, a1 = 0.f;   // cols 2*lane, 2*lane+1
    float b0 = 0.f, b1 = 0.f;
    for (int chunk = beg; chunk < end; chunk += 64) {
        const int cnt = min(64, end - chunk);
        const int sv = (lane < cnt) ? csr_src[chunk + lane] : 0;
        int j = 0;
        for (; j + 4 <= cnt; j += 4) {
            const int s0 = __shfl(sv, j + 0);
            const int s1 = __shfl(sv, j + 1);
            const int s2 = __shfl(sv, j + 2);
            const int s3 = __shfl(sv, j + 3);
            const unsigned int v0 = *reinterpret_cast<const unsigned int*>(h + (size_t)s0 * DH + lane * 2);
            const unsigned int v1 = *reinterpret_cast<const unsigned int*>(h + (size_t)s1 * DH + lane * 2);
            const unsigned int v2 = *reinterpret_cast<const unsigned int*>(h + (size_t)s2 * DH + lane * 2);
            const unsigned int v3 = *reinterpret_cast<const unsigned int*>(h + (size_t)s3 * DH + lane * 2);
            union { unsigned int u; float f; } t;
            t.u = v0 << 16; a0 += t.f;  t.u = v0 & 0xFFFF0000u; a1 += t.f;
            t.u = v1 << 16; b0 += t.f;  t.u = v1 & 0xFFFF0000u; b1 += t.f;
            t.u = v2 << 16; a0 += t.f;  t.u = v2 & 0xFFFF0000u; a1 += t.f;
            t.u = v3 << 16; b0 += t.f;  t.u = v3 & 0xFFFF0000u; b1 += t.f;
        }
        for (; j < cnt; ++j) {
            const int s = __shfl(sv, j);
            const unsigned int v = *reinterpret_cast<const unsigned int*>(h + (size_t)s * DH + lane * 2);
            union { unsigned int u; float f; } t;
            t.u = v << 16; a0 += t.f;  t.u = v & 0xFFFF0000u; a1 += t.f;
        }
    }
    float o0 = a0 + b0, o1 = a1 + b1;
    if (useScale) {
        const float sc = deg_inv[node];
        o0 *= sc; o1 *= sc;
    }
    const unsigned int packed = (unsigned int)f2bf(o0) | ((unsigned int)f2bf(o1) << 16);
    reinterpret_cast<unsigned int*>(agg + (size_t)node * DH)[lane] = packed;
}

// ---------------- weight fragment packing (once per launch) ----------------
// wfrag[layer][phase][t][n][lane][j] = bf16(W[t*32 + (lane>>4)*8 + j][n*16 + (lane&15)])
__global__ void pack_w_kernel(const float* __restrict__ cwr, const float* __restrict__ cwroot,
                              const float* __restrict__ swl, const float* __restrict__ swr,
                              unsigned short* __restrict__ wfrag) {
    const int g = blockIdx.x * blockDim.x + threadIdx.x;
    if (g >= 16384) return;
    const int lane = g & 63;
    const int n = (g >> 6) & 7;
    const int t = (g >> 9) & 3;
    const int phase = (g >> 11) & 1;
    const int layer = (g >> 12) & 3;
    const float* W1 = (layer < 2) ? (cwr + layer * 16384) : (swl + (layer - 2) * 16384);
    const float* W2 = (layer < 2) ? (cwroot + layer * 16384) : (swr + (layer - 2) * 16384);
    const float* W = phase ? W2 : W1;
    const int col = n * 16 + (lane & 15);
    const int k0 = t * 32 + (lane >> 4) * 8;
    unsigned short v[8];
#pragma unroll
    for (int j = 0; j < 8; ++j) v[j] = f2bf(W[(size_t)(k0 + j) * DH + col]);
    unsigned short* dst = wfrag + ((((size_t)g)) * 8);  // g already == linear (layer,phase,t,n,lane)
#pragma unroll
    for (int j = 0; j < 8; ++j) dst[j] = v[j];
}

// ---------------- fused layer via MFMA: C = act(A1@W1 + A2@W2 + bias) ----------------
// A1,A2: [N][128] bf16.  Wf: fragment-packed (see pack_w_kernel), 2 phases.
// Output: bf16 to Cb if relu path, fp32 to Cf for the last layer.
__global__ __launch_bounds__(256) void fused_layer_mfma_kernel(
    const unsigned short* __restrict__ A1, const unsigned short* __restrict__ A2,
    const unsigned short* __restrict__ Wf, const float* __restrict__ bias,
    unsigned short* __restrict__ Cb, float* __restrict__ Cf, const int relu) {
    const int wid = threadIdx.x >> 6;          // wave 0..3
    const int lane = threadIdx.x & 63;
    const int row0 = blockIdx.x * 64 + wid * 16;
    const int arow = row0 + (lane & 15);
    const int koff = (lane >> 4) * 8;          // 0,8,16,24
    const bool rowOK = (arow < N_NODES);

    f32x4 acc[8];
#pragma unroll
    for (int n = 0; n < 8; ++n) acc[n] = (f32x4){0.f, 0.f, 0.f, 0.f};

#pragma unroll
    for (int phase = 0; phase < 2; ++phase) {
        const unsigned short* Ar = (phase ? A2 : A1) + (size_t)arow * DH;
        const unsigned short* Wp = Wf + (size_t)phase * (4 * 8 * 64 * 8);
#pragma unroll
        for (int t = 0; t < 4; ++t) {
            bf16x8 af = {};
            if (rowOK) af = *reinterpret_cast<const bf16x8*>(Ar + t * 32 + koff);
            const unsigned short* wt = Wp + (((size_t)t * 8) * 64 + lane) * 8;
#pragma unroll
            for (int n = 0; n < 8; ++n) {
                const bf16x8 bfv = *reinterpret_cast<const bf16x8*>(wt + (size_t)n * 64 * 8);
                acc[n] = __builtin_amdgcn_mfma_f32_16x16x32_bf16(af, bfv, acc[n], 0, 0, 0);
            }
        }
    }

    // D mapping: col = n*16 + (lane&15), row = row0 + (lane>>4)*4 + r
    const int crow0 = row0 + (lane >> 4) * 4;
    const int ccol = lane & 15;
#pragma unroll
    for (int n = 0; n < 8; ++n) {
        const int col = n * 16 + ccol;
        const float bv = bias[col];
#pragma unroll
        for (int r = 0; r < 4; ++r) {
            const int grow = crow0 + r;
            if (grow >= N_NODES) continue;
            float v = acc[n][r] + bv;
            if (relu) {
                v = fmaxf(v, 0.f);
                Cb[(size_t)grow * DH + col] = f2bf(v);
            } else {
                Cf[(size_t)grow * DH + col] = v;
            }
        }
    }
}

// ---------------- segmented pooling (batch is sorted) ----------------
#define POOL_BLOCKS 512
__global__ __launch_bounds__(128) void pool_seg_kernel(const float* __restrict__ h,
                                                       const int* __restrict__ batch,
                                                       float* __restrict__ pooled,
                                                       float* __restrict__ cnt) {
    const int c = threadIdx.x;
    const int nper = (N_NODES + POOL_BLOCKS - 1) / POOL_BLOCKS;
    const int n0 = blockIdx.x * nper;
    const int n1 = min(n0 + nper, N_NODES);
    if (n0 >= n1) return;
    float acc = 0.f;
    int g = batch[n0];
    int runlen = 0;
    for (int n = n0; n < n1; ++n) {
        const int bg = batch[n];
        if (bg != g) {
            atomicAdd(&pooled[(size_t)g * DH + c], acc);
            if (c == 0) atomicAdd(&cnt[g], (float)runlen);
            acc = 0.f; runlen = 0; g = bg;
        }
        acc += h[(size_t)n * DH + c];
        ++runlen;
    }
    atomicAdd(&pooled[(size_t)g * DH + c], acc);
    if (c == 0) atomicAdd(&cnt[g], (float)runlen);
}

__global__ void final_kernel(const float* __restrict__ pooled, const float* __restrict__ cnt,
                             const float* __restrict__ fcw, const float* __restrict__ fcb,
                             float* __restrict__ out) {
    const int g = blockIdx.x;
    const int j = threadIdx.x;
    if (j >= DOUT) return;
    const float inv = 1.0f / fmaxf(cnt[g], 1.0f);
    float acc = fcb[j];
    for (int d = 0; d < DH; ++d)
        acc = fmaf(pooled[(size_t)g * DH + d] * inv, fcw[(size_t)d * DOUT + j], acc);
    out[(size_t)g * DOUT + j] = acc;
}

// ---------------- host ----------------
extern "C" void kernel_launch(void* const* d_in, const int* in_sizes, int n_in,
                              void* d_out, int out_size, void* d_ws, size_t ws_size,
                              hipStream_t stream) {
    const float* x = (const float*)d_in[0];
    const int* ei = (const int*)d_in[1];
    const int* batch = (const int*)d_in[2];
    const float* conv_w_rel = (const float*)d_in[3];
    const float* conv_b_rel = (const float*)d_in[4];
    const float* conv_w_root = (const float*)d_in[5];
    const float* sage_w_l = (const float*)d_in[6];
    const float* sage_b_l = (const float*)d_in[7];
    const float* sage_w_r = (const float*)d_in[8];
    const float* fc_w = (const float*)d_in[9];
    const float* fc_b = (const float*)d_in[10];
    float* out = (float*)d_out;

    const int* src = ei;
    const int* dst = ei + N_EDGES;

    const size_t NHB = (size_t)N_NODES * DH * sizeof(unsigned short);  // 12.8 MB
    const size_t NFB = (size_t)N_NODES * DH * sizeof(float);           // 25.6 MB
    char* p = (char*)d_ws;
    unsigned short* hb0 = (unsigned short*)p; p += NHB;
    unsigned short* hb1 = (unsigned short*)p; p += NHB;
    unsigned short* aggb = (unsigned short*)p; p += NHB;
    float* hF = (float*)p; p += NFB;
    float* deg_inv = (float*)p; p += ((size_t)N_NODES * sizeof(float) + 255) & ~(size_t)255;
    float* stat = (float*)p; p += 512 * sizeof(float);
    float* pooled = (float*)p; p += (size_t)N_GRAPHS * DH * sizeof(float);
    float* cnt = (float*)p; p += ((size_t)N_GRAPHS * sizeof(float) + 255) & ~(size_t)255;
    int* deg_i = (int*)p; p += ((size_t)N_NODES * sizeof(int) + 255) & ~(size_t)255;
    int* row_ptr = (int*)p; p += ((size_t)(N_NODES + 1) * sizeof(int) + 255) & ~(size_t)255;
    int* cursor = (int*)p; p += ((size_t)N_NODES * sizeof(int) + 255) & ~(size_t)255;
    int* bsum = (int*)p; p += ((size_t)SCAN_BLK * sizeof(int) + 255) & ~(size_t)255;
    float* partial = (float*)p; p += (size_t)256 * STAT_BLKS * sizeof(float);
    unsigned short* wfrag = (unsigned short*)p; p += (size_t)4 * 32768 * sizeof(unsigned short);
    int* csr_src = (int*)p; p += (size_t)N_EDGES * sizeof(int);

    // --- stats + standardize (-> bf16 h0) ---
    hipLaunchKernelGGL(stats_kernel, dim3(STAT_BLKS), dim3(256), 0, stream, x, partial);
    hipLaunchKernelGGL(finalize_stats_kernel, dim3(1), dim3(DH), 0, stream, partial, stat);
    hipLaunchKernelGGL(standardize_kernel, dim3((N_NODES * DH / 4) / 256), dim3(256), 0, stream,
                       x, stat, hb0);

    // --- weight fragment packing (bf16, MFMA lane order) ---
    hipLaunchKernelGGL(pack_w_kernel, dim3(64), dim3(256), 0, stream,
                       conv_w_rel, conv_w_root, sage_w_l, sage_w_r, wfrag);

    // --- CSR build (once; reused by all 4 layers) ---
    hipMemsetAsync(deg_i, 0, (size_t)N_NODES * sizeof(int), stream);
    hipLaunchKernelGGL(count_deg_kernel, dim3((N_EDGES + 255) / 256), dim3(256), 0, stream,
                       dst, deg_i);
    hipLaunchKernelGGL(scan_local_kernel, dim3(SCAN_NBLK), dim3(SCAN_BLK), 0, stream,
                       deg_i, row_ptr, bsum);
    hipLaunchKernelGGL(scan_bsum_kernel, dim3(1), dim3(SCAN_BLK), 0, stream, bsum);
    hipLaunchKernelGGL(scan_finalize_kernel, dim3(SCAN_NBLK), dim3(SCAN_BLK), 0, stream,
                       deg_i, bsum, row_ptr, cursor, deg_inv);
    hipLaunchKernelGGL(scatter_kernel, dim3((N_EDGES + 255) / 256), dim3(256), 0, stream,
                       src, dst, cursor, csr_src);

    // --- 4 layers ---
    const float* Bs[4] = {conv_b_rel, conv_b_rel + 128, sage_b_l, sage_b_l + 128};

    unsigned short* curb = hb0;
    unsigned short* nxtb = hb1;
    const dim3 aggGrid((N_NODES + 3) / 4);
    const dim3 gemmGrid((N_NODES + 63) / 64);
    for (int l = 0; l < 4; ++l) {
        hipLaunchKernelGGL(aggregate_csr_kernel, aggGrid, dim3(256), 0, stream,
                           curb, row_ptr, csr_src, deg_inv, aggb, (l >= 2) ? 1 : 0);
        hipLaunchKernelGGL(fused_layer_mfma_kernel, gemmGrid, dim3(256), 0, stream,
                           aggb, curb, wfrag + (size_t)l * 32768, Bs[l],
                           (l < 3) ? nxtb : (unsigned short*)nullptr,
                           (l < 3) ? (float*)nullptr : hF,
                           (l < 3) ? 1 : 0);
        unsigned short* t = curb; curb = nxtb; nxtb = t;
    }

    // --- pool + fc ---
    hipMemsetAsync(pooled, 0, ((size_t)N_GRAPHS * DH + N_GRAPHS) * sizeof(float), stream);
    hipLaunchKernelGGL(pool_seg_kernel, dim3(POOL_BLOCKS), dim3(DH), 0, stream,
                       hF, batch, pooled, cnt);
    hipLaunchKernelGGL(final_kernel, dim3(N_GRAPHS), dim3(64), 0, stream,
                       pooled, cnt, fc_w, fc_b, out);
}

// Round 8
// 358.371 us; speedup vs baseline: 1.0292x; 1.0292x over previous
//
#include <hip/hip_runtime.h>

#define N_NODES 50000
#define N_EDGES 800000
#define N_GRAPHS 64
#define DH 128
#define DOUT 32

typedef __attribute__((ext_vector_type(8))) short bf16x8;
typedef __attribute__((ext_vector_type(4))) float f32x4;

__device__ __forceinline__ unsigned short f2bf(float f) {
    union { float f; unsigned int u; } x;
    x.f = f;
    unsigned int u = x.u;
    u += 0x7FFFu + ((u >> 16) & 1u);  // round-to-nearest-even
    return (unsigned short)(u >> 16);
}

// ---------------- stats: column sums / sumsq (no atomics, 2-stage) ----------------
#define STAT_BLKS 512
__global__ __launch_bounds__(256) void stats_kernel(const float* __restrict__ x,
                                                    float* __restrict__ partial) {
    __shared__ float4 shs[256];
    __shared__ float4 shq[256];
    const int tid = threadIdx.x;
    const int rowgrp = tid >> 5;
    const int cq = tid & 31;
    float4 s = make_float4(0.f, 0.f, 0.f, 0.f);
    float4 q = make_float4(0.f, 0.f, 0.f, 0.f);
#pragma unroll 4
    for (int r = blockIdx.x * 8 + rowgrp; r < N_NODES; r += STAT_BLKS * 8) {
        const float4 v = *reinterpret_cast<const float4*>(x + (size_t)r * DH + cq * 4);
        s.x += v.x; s.y += v.y; s.z += v.z; s.w += v.w;
        q.x = fmaf(v.x, v.x, q.x); q.y = fmaf(v.y, v.y, q.y);
        q.z = fmaf(v.z, v.z, q.z); q.w = fmaf(v.w, v.w, q.w);
    }
    shs[tid] = s; shq[tid] = q;
    __syncthreads();
    for (int off = 128; off >= 32; off >>= 1) {
        if (tid < off) {
            float4 a = shs[tid], b = shs[tid + off];
            a.x += b.x; a.y += b.y; a.z += b.z; a.w += b.w;
            shs[tid] = a;
            float4 c = shq[tid], d = shq[tid + off];
            c.x += d.x; c.y += d.y; c.z += d.z; c.w += d.w;
            shq[tid] = c;
        }
        __syncthreads();
    }
    if (tid < 32) {
        const float4 a = shs[tid];
        const float4 c = shq[tid];
        const float sv[4] = {a.x, a.y, a.z, a.w};
        const float qv[4] = {c.x, c.y, c.z, c.w};
#pragma unroll
        for (int j = 0; j < 4; ++j) {
            const int col = tid * 4 + j;
            partial[(size_t)col * STAT_BLKS + blockIdx.x] = sv[j];
            partial[(size_t)(128 + col) * STAT_BLKS + blockIdx.x] = qv[j];
        }
    }
}

// stat layout: [256:384) mu, [384:512) inv_sd
__global__ __launch_bounds__(128) void finalize_stats_kernel(const float* __restrict__ partial,
                                                             float* __restrict__ stat) {
    const int c = threadIdx.x;
    const float4* ps = reinterpret_cast<const float4*>(partial + (size_t)c * STAT_BLKS);
    const float4* pq = reinterpret_cast<const float4*>(partial + (size_t)(128 + c) * STAT_BLKS);
    float s = 0.f, q = 0.f;
#pragma unroll 8
    for (int b = 0; b < STAT_BLKS / 4; ++b) {
        const float4 v = ps[b];
        s += v.x + v.y + v.z + v.w;
        const float4 w = pq[b];
        q += w.x + w.y + w.z + w.w;
    }
    const float inv_n = 1.0f / (float)N_NODES;
    const float mu = s * inv_n;
    const float var = q * inv_n - mu * mu;
    const float sd = sqrtf(fmaxf(var, 1e-20f));
    stat[256 + c] = mu;
    stat[384 + c] = 1.0f / sd;
}

// standardize -> bf16 h
__global__ void standardize_kernel(const float* __restrict__ x,
                                   const float* __restrict__ stat,
                                   unsigned short* __restrict__ h) {
    const size_t i = (size_t)blockIdx.x * blockDim.x + threadIdx.x;  // float4 index
    const int c4 = (int)(i & 31) << 2;
    const float4 v = reinterpret_cast<const float4*>(x)[i];
    const float4 m = *reinterpret_cast<const float4*>(stat + 256 + c4);
    const float4 is = *reinterpret_cast<const float4*>(stat + 384 + c4);
    ushort4 o;
    o.x = f2bf((v.x - m.x) * is.x);
    o.y = f2bf((v.y - m.y) * is.y);
    o.z = f2bf((v.z - m.z) * is.z);
    o.w = f2bf((v.w - m.w) * is.w);
    reinterpret_cast<ushort4*>(h)[i] = o;
}

// ---------------- CSR build ----------------
__global__ void count_deg_kernel(const int* __restrict__ dst, int* __restrict__ deg_i) {
    int e = blockIdx.x * blockDim.x + threadIdx.x;
    if (e < N_EDGES) atomicAdd(&deg_i[dst[e]], 1);
}

#define SCAN_BLK 256
#define SCAN_NBLK ((N_NODES + SCAN_BLK - 1) / SCAN_BLK)  // 196

__global__ __launch_bounds__(SCAN_BLK) void scan_local_kernel(const int* __restrict__ deg_i,
                                                              int* __restrict__ row_ptr,
                                                              int* __restrict__ bsum) {
    __shared__ int sh[SCAN_BLK];
    const int tid = threadIdx.x;
    const int idx = blockIdx.x * SCAN_BLK + tid;
    const int v = (idx < N_NODES) ? deg_i[idx] : 0;
    sh[tid] = v;
    __syncthreads();
#pragma unroll
    for (int off = 1; off < SCAN_BLK; off <<= 1) {
        const int t = (tid >= off) ? sh[tid - off] : 0;
        __syncthreads();
        sh[tid] += t;
        __syncthreads();
    }
    if (idx < N_NODES) row_ptr[idx] = sh[tid] - v;
    if (tid == SCAN_BLK - 1) bsum[blockIdx.x] = sh[tid];
}

__global__ __launch_bounds__(SCAN_BLK) void scan_bsum_kernel(int* __restrict__ bsum) {
    __shared__ int sh[SCAN_BLK];
    const int tid = threadIdx.x;
    const int v = (tid < SCAN_NBLK) ? bsum[tid] : 0;
    sh[tid] = v;
    __syncthreads();
#pragma unroll
    for (int off = 1; off < SCAN_BLK; off <<= 1) {
        const int t = (tid >= off) ? sh[tid - off] : 0;
        __syncthreads();
        sh[tid] += t;
        __syncthreads();
    }
    if (tid < SCAN_NBLK) bsum[tid] = sh[tid] - v;
}

__global__ __launch_bounds__(SCAN_BLK) void scan_finalize_kernel(const int* __restrict__ deg_i,
                                                                 const int* __restrict__ bsum,
                                                                 int* __restrict__ row_ptr,
                                                                 int* __restrict__ cursor,
                                                                 float* __restrict__ deg_inv) {
    const int tid = threadIdx.x;
    const int idx = blockIdx.x * SCAN_BLK + tid;
    if (idx < N_NODES) {
        const int excl = row_ptr[idx] + bsum[blockIdx.x];
        row_ptr[idx] = excl;
        cursor[idx] = excl;
        const int d = deg_i[idx];
        deg_inv[idx] = 1.0f / (float)(d > 1 ? d : 1);
    }
    if (idx == 0) row_ptr[N_NODES] = N_EDGES;
}

// ---- XCD-ranged scatter: range = blockIdx % 8 -> one XCD owns one 400KB csr window ----
#define NXCD 8
#define RANGE_NODES ((N_NODES + NXCD - 1) / NXCD)  // 6250
#define SC_SLICES 104                              // blocks per range; grid = 8*104
__global__ __launch_bounds__(256) void scatter_ranged_kernel(const int* __restrict__ src,
                                                             const int* __restrict__ dst,
                                                             int* __restrict__ cursor,
                                                             int* __restrict__ csr_src) {
    const int range = blockIdx.x & (NXCD - 1);
    const int slice = blockIdx.x >> 3;
    const int lo = range * RANGE_NODES;
    const int hi = min(lo + RANGE_NODES, N_NODES);
    const int stride = SC_SLICES * 256;
    for (int e = slice * 256 + threadIdx.x; e < N_EDGES; e += stride) {
        const int d = dst[e];
        if (d >= lo && d < hi) {
            const int pos = atomicAdd(&cursor[d], 1);
            csr_src[pos] = src[e];
        }
    }
}

// ---------------- aggregation via CSR (bf16 in, fp32 accum, bf16 out) ----------------
// agg[n] = (useScale ? deg_inv[n] : 1) * sum_{e in in(n)} h[src[e]]
__global__ __launch_bounds__(256) void aggregate_csr_kernel(const unsigned short* __restrict__ h,
                                                            const int* __restrict__ row_ptr,
                                                            const int* __restrict__ csr_src,
                                                            const float* __restrict__ deg_inv,
                                                            unsigned short* __restrict__ agg,
                                                            const int useScale) {
    const int node = blockIdx.x * 4 + (threadIdx.x >> 6);  // one wave per node
    if (node >= N_NODES) return;
    const int lane = threadIdx.x & 63;
    const int beg = row_ptr[node];
    const int end = row_ptr[node + 1];
    float a0 = 0.f, a1 = 0.f;   // cols 2*lane, 2*lane+1
    for (int chunk = beg; chunk < end; chunk += 64) {
        const int cnt = min(64, end - chunk);
        const int sv = (lane < cnt) ? csr_src[chunk + lane] : 0;
        int j = 0;
        for (; j + 8 <= cnt; j += 8) {
            int ss[8];
#pragma unroll
            for (int u = 0; u < 8; ++u) ss[u] = __shfl(sv, j + u);
            unsigned int vv[8];
#pragma unroll
            for (int u = 0; u < 8; ++u)
                vv[u] = *reinterpret_cast<const unsigned int*>(h + (size_t)ss[u] * DH + lane * 2);
#pragma unroll
            for (int u = 0; u < 8; ++u) {
                union { unsigned int x; float f; } t;
                t.x = vv[u] << 16; a0 += t.f;
                t.x = vv[u] & 0xFFFF0000u; a1 += t.f;
            }
        }
        for (; j < cnt; ++j) {
            const int s = __shfl(sv, j);
            const unsigned int v = *reinterpret_cast<const unsigned int*>(h + (size_t)s * DH + lane * 2);
            union { unsigned int x; float f; } t;
            t.x = v << 16; a0 += t.f;
            t.x = v & 0xFFFF0000u; a1 += t.f;
        }
    }
    float o0 = a0, o1 = a1;
    if (useScale) {
        const float sc = deg_inv[node];
        o0 *= sc; o1 *= sc;
    }
    const unsigned int packed = (unsigned int)f2bf(o0) | ((unsigned int)f2bf(o1) << 16);
    reinterpret_cast<unsigned int*>(agg + (size_t)node * DH)[lane] = packed;
}

// ---------------- weight fragment packing (once per launch) ----------------
__global__ void pack_w_kernel(const float* __restrict__ cwr, const float* __restrict__ cwroot,
                              const float* __restrict__ swl, const float* __restrict__ swr,
                              unsigned short* __restrict__ wfrag) {
    const int g = blockIdx.x * blockDim.x + threadIdx.x;
    if (g >= 16384) return;
    const int lane = g & 63;
    const int n = (g >> 6) & 7;
    const int t = (g >> 9) & 3;
    const int phase = (g >> 11) & 1;
    const int layer = (g >> 12) & 3;
    const float* W1 = (layer < 2) ? (cwr + layer * 16384) : (swl + (layer - 2) * 16384);
    const float* W2 = (layer < 2) ? (cwroot + layer * 16384) : (swr + (layer - 2) * 16384);
    const float* W = phase ? W2 : W1;
    const int col = n * 16 + (lane & 15);
    const int k0 = t * 32 + (lane >> 4) * 8;
    unsigned short v[8];
#pragma unroll
    for (int j = 0; j < 8; ++j) v[j] = f2bf(W[(size_t)(k0 + j) * DH + col]);
    unsigned short* dstp = wfrag + ((size_t)g * 8);
#pragma unroll
    for (int j = 0; j < 8; ++j) dstp[j] = v[j];
}

// ---------------- fused layer via MFMA: C = act(A1@W1 + A2@W2 + bias) ----------------
__global__ __launch_bounds__(256) void fused_layer_mfma_kernel(
    const unsigned short* __restrict__ A1, const unsigned short* __restrict__ A2,
    const unsigned short* __restrict__ Wf, const float* __restrict__ bias,
    unsigned short* __restrict__ Cb, float* __restrict__ Cf, const int relu) {
    const int wid = threadIdx.x >> 6;          // wave 0..3
    const int lane = threadIdx.x & 63;
    const int row0 = blockIdx.x * 64 + wid * 16;
    const int arow = row0 + (lane & 15);
    const int koff = (lane >> 4) * 8;          // 0,8,16,24
    const bool rowOK = (arow < N_NODES);

    f32x4 acc[8];
#pragma unroll
    for (int n = 0; n < 8; ++n) acc[n] = (f32x4){0.f, 0.f, 0.f, 0.f};

#pragma unroll
    for (int phase = 0; phase < 2; ++phase) {
        const unsigned short* Ar = (phase ? A2 : A1) + (size_t)arow * DH;
        const unsigned short* Wp = Wf + (size_t)phase * (4 * 8 * 64 * 8);
#pragma unroll
        for (int t = 0; t < 4; ++t) {
            bf16x8 af = {};
            if (rowOK) af = *reinterpret_cast<const bf16x8*>(Ar + t * 32 + koff);
            const unsigned short* wt = Wp + (((size_t)t * 8) * 64 + lane) * 8;
#pragma unroll
            for (int n = 0; n < 8; ++n) {
                const bf16x8 bfv = *reinterpret_cast<const bf16x8*>(wt + (size_t)n * 64 * 8);
                acc[n] = __builtin_amdgcn_mfma_f32_16x16x32_bf16(af, bfv, acc[n], 0, 0, 0);
            }
        }
    }

    const int crow0 = row0 + (lane >> 4) * 4;
    const int ccol = lane & 15;
#pragma unroll
    for (int n = 0; n < 8; ++n) {
        const int col = n * 16 + ccol;
        const float bv = bias[col];
#pragma unroll
        for (int r = 0; r < 4; ++r) {
            const int grow = crow0 + r;
            if (grow >= N_NODES) continue;
            float v = acc[n][r] + bv;
            if (relu) {
                v = fmaxf(v, 0.f);
                Cb[(size_t)grow * DH + col] = f2bf(v);
            } else {
                Cf[(size_t)grow * DH + col] = v;
            }
        }
    }
}

// ---------------- segmented pooling (batch is sorted) ----------------
#define POOL_BLOCKS 512
__global__ __launch_bounds__(128) void pool_seg_kernel(const float* __restrict__ h,
                                                       const int* __restrict__ batch,
                                                       float* __restrict__ pooled,
                                                       float* __restrict__ cnt) {
    const int c = threadIdx.x;
    const int nper = (N_NODES + POOL_BLOCKS - 1) / POOL_BLOCKS;
    const int n0 = blockIdx.x * nper;
    const int n1 = min(n0 + nper, N_NODES);
    if (n0 >= n1) return;
    float acc = 0.f;
    int g = batch[n0];
    int runlen = 0;
    for (int n = n0; n < n1; ++n) {
        const int bg = batch[n];
        if (bg != g) {
            atomicAdd(&pooled[(size_t)g * DH + c], acc);
            if (c == 0) atomicAdd(&cnt[g], (float)runlen);
            acc = 0.f; runlen = 0; g = bg;
        }
        acc += h[(size_t)n * DH + c];
        ++runlen;
    }
    atomicAdd(&pooled[(size_t)g * DH + c], acc);
    if (c == 0) atomicAdd(&cnt[g], (float)runlen);
}

__global__ void final_kernel(const float* __restrict__ pooled, const float* __restrict__ cnt,
                             const float* __restrict__ fcw, const float* __restrict__ fcb,
                             float* __restrict__ out) {
    const int g = blockIdx.x;
    const int j = threadIdx.x;
    if (j >= DOUT) return;
    const float inv = 1.0f / fmaxf(cnt[g], 1.0f);
    float acc = fcb[j];
    for (int d = 0; d < DH; ++d)
        acc = fmaf(pooled[(size_t)g * DH + d] * inv, fcw[(size_t)d * DOUT + j], acc);
    out[(size_t)g * DOUT + j] = acc;
}

// ---------------- host ----------------
extern "C" void kernel_launch(void* const* d_in, const int* in_sizes, int n_in,
                              void* d_out, int out_size, void* d_ws, size_t ws_size,
                              hipStream_t stream) {
    const float* x = (const float*)d_in[0];
    const int* ei = (const int*)d_in[1];
    const int* batch = (const int*)d_in[2];
    const float* conv_w_rel = (const float*)d_in[3];
    const float* conv_b_rel = (const float*)d_in[4];
    const float* conv_w_root = (const float*)d_in[5];
    const float* sage_w_l = (const float*)d_in[6];
    const float* sage_b_l = (const float*)d_in[7];
    const float* sage_w_r = (const float*)d_in[8];
    const float* fc_w = (const float*)d_in[9];
    const float* fc_b = (const float*)d_in[10];
    float* out = (float*)d_out;

    const int* src = ei;
    const int* dst = ei + N_EDGES;

    const size_t NHB = (size_t)N_NODES * DH * sizeof(unsigned short);  // 12.8 MB
    const size_t NFB = (size_t)N_NODES * DH * sizeof(float);           // 25.6 MB
    char* p = (char*)d_ws;
    unsigned short* hb0 = (unsigned short*)p; p += NHB;
    unsigned short* hb1 = (unsigned short*)p; p += NHB;
    unsigned short* aggb = (unsigned short*)p; p += NHB;
    float* hF = (float*)p; p += NFB;
    float* deg_inv = (float*)p; p += ((size_t)N_NODES * sizeof(float) + 255) & ~(size_t)255;
    float* stat = (float*)p; p += 512 * sizeof(float);
    float* pooled = (float*)p; p += (size_t)N_GRAPHS * DH * sizeof(float);
    float* cnt = (float*)p; p += ((size_t)N_GRAPHS * sizeof(float) + 255) & ~(size_t)255;
    int* deg_i = (int*)p; p += ((size_t)N_NODES * sizeof(int) + 255) & ~(size_t)255;
    int* row_ptr = (int*)p; p += ((size_t)(N_NODES + 1) * sizeof(int) + 255) & ~(size_t)255;
    int* cursor = (int*)p; p += ((size_t)N_NODES * sizeof(int) + 255) & ~(size_t)255;
    int* bsum = (int*)p; p += ((size_t)SCAN_BLK * sizeof(int) + 255) & ~(size_t)255;
    float* partial = (float*)p; p += (size_t)256 * STAT_BLKS * sizeof(float);
    unsigned short* wfrag = (unsigned short*)p; p += (size_t)4 * 32768 * sizeof(unsigned short);
    int* csr_src = (int*)p; p += (size_t)N_EDGES * sizeof(int);

    // --- stats + standardize (-> bf16 h0) ---
    hipLaunchKernelGGL(stats_kernel, dim3(STAT_BLKS), dim3(256), 0, stream, x, partial);
    hipLaunchKernelGGL(finalize_stats_kernel, dim3(1), dim3(DH), 0, stream, partial, stat);
    hipLaunchKernelGGL(standardize_kernel, dim3((N_NODES * DH / 4) / 256), dim3(256), 0, stream,
                       x, stat, hb0);

    // --- weight fragment packing (bf16, MFMA lane order) ---
    hipLaunchKernelGGL(pack_w_kernel, dim3(64), dim3(256), 0, stream,
                       conv_w_rel, conv_w_root, sage_w_l, sage_w_r, wfrag);

    // --- CSR build (once; reused by all 4 layers) ---
    hipMemsetAsync(deg_i, 0, (size_t)N_NODES * sizeof(int), stream);
    hipLaunchKernelGGL(count_deg_kernel, dim3((N_EDGES + 255) / 256), dim3(256), 0, stream,
                       dst, deg_i);
    hipLaunchKernelGGL(scan_local_kernel, dim3(SCAN_NBLK), dim3(SCAN_BLK), 0, stream,
                       deg_i, row_ptr, bsum);
    hipLaunchKernelGGL(scan_bsum_kernel, dim3(1), dim3(SCAN_BLK), 0, stream, bsum);
    hipLaunchKernelGGL(scan_finalize_kernel, dim3(SCAN_NBLK), dim3(SCAN_BLK), 0, stream,
                       deg_i, bsum, row_ptr, cursor, deg_inv);
    hipLaunchKernelGGL(scatter_ranged_kernel, dim3(NXCD * SC_SLICES), dim3(256), 0, stream,
                       src, dst, cursor, csr_src);

    // --- 4 layers ---
    const float* Bs[4] = {conv_b_rel, conv_b_rel + 128, sage_b_l, sage_b_l + 128};

    unsigned short* curb = hb0;
    unsigned short* nxtb = hb1;
    const dim3 aggGrid((N_NODES + 3) / 4);
    const dim3 gemmGrid((N_NODES + 63) / 64);
    for (int l = 0; l < 4; ++l) {
        hipLaunchKernelGGL(aggregate_csr_kernel, aggGrid, dim3(256), 0, stream,
                           curb, row_ptr, csr_src, deg_inv, aggb, (l >= 2) ? 1 : 0);
        hipLaunchKernelGGL(fused_layer_mfma_kernel, gemmGrid, dim3(256), 0, stream,
                           aggb, curb, wfrag + (size_t)l * 32768, Bs[l],
                           (l < 3) ? nxtb : (unsigned short*)nullptr,
                           (l < 3) ? (float*)nullptr : hF,
                           (l < 3) ? 1 : 0);
        unsigned short* t = curb; curb = nxtb; nxtb = t;
    }

    // --- pool + fc ---
    hipMemsetAsync(pooled, 0, ((size_t)N_GRAPHS * DH + N_GRAPHS) * sizeof(float), stream);
    hipLaunchKernelGGL(pool_seg_kernel, dim3(POOL_BLOCKS), dim3(DH), 0, stream,
                       hF, batch, pooled, cnt);
    hipLaunchKernelGGL(final_kernel, dim3(N_GRAPHS), dim3(64), 0, stream,
                       pooled, cnt, fc_w, fc_b, out);
}